// Round 2
// baseline (9316.179 us; speedup 1.0000x reference)
//
#include <hip/hip_runtime.h>
#include <hip/hip_fp16.h>

typedef _Float16 f16;
typedef _Float16 f16x8 __attribute__((ext_vector_type(8)));
typedef _Float16 f16x4 __attribute__((ext_vector_type(4)));
typedef float f32x4v __attribute__((ext_vector_type(4)));

#define S_LEN 1024
#define NS 512
#define NV 32000
#define NCU 4
#define NOWN (NS / NCU)   // 128 n-columns per CU

#define MFMA16(a, b, c) __builtin_amdgcn_mfma_f32_16x16x32_f16((a), (b), (c), 0, 0, 0)

// ---------------------------------------------------------------------------
// ws layout:
//   u16   : [1024][4][512] f16  at 0          (4 MB)    u[s][b][n]
//   st16  : [1024][4][512] f16  at 4 MB       (4 MB)    states[s][b][n]
//   bT16  : [512][512]     f16  at 8 MB       (512 KB)  bT16[n][e] = b[e][n]
//   flags : unsigned[8]         at 8 MB+512KB (zeroed every launch)
//   X     : u64[2][512]         at +256       exchange: packed 4xf16 per n
// ---------------------------------------------------------------------------

__global__ __launch_bounds__(256) void transpose512_f16_kernel(
        const float* __restrict__ src, f16* __restrict__ dstT,
        unsigned* __restrict__ flags) {
    int idx = blockIdx.x * 256 + threadIdx.x;
    if (idx < 8) flags[idx] = 0;     // reset sync flags every launch (graph-safe)
    int r = idx >> 9;
    int c = idx & 511;
    dstT[c * 512 + r] = (f16)src[idx];
}

// ---------------------------------------------------------------------------
// embed + input projection: u[m][n] = sum_e emb[x[m]][e] * b[e][n], m = s*4+b
// ---------------------------------------------------------------------------
__global__ __launch_bounds__(256) void embu_kernel(
        const int* __restrict__ x, const float* __restrict__ emb,
        const f16* __restrict__ bT, f16* __restrict__ u16) {
    __shared__ f16 embA[64 * 40];
    __shared__ f16 Bt[512 * 40];
    __shared__ int xi[64];

    int t = threadIdx.x;
    int wg = blockIdx.x;
    if (t < 64) {
        int m = wg * 64 + t;
        int bb = m & 3, ss = m >> 2;
        xi[t] = x[bb * S_LEN + ss];
    }
    __syncthreads();

    int wv = t >> 6, l = t & 63, lr = l & 15, lg = l >> 4;

    f32x4v acc[32];
#pragma unroll
    for (int i = 0; i < 32; i++) acc[i] = (f32x4v){0.f, 0.f, 0.f, 0.f};

    for (int kc = 0; kc < 512; kc += 32) {
        __syncthreads();
        {
            int tk = t >> 2, c0 = (t & 3) * 8;
            const float* src = emb + (size_t)xi[tk] * NS + kc + c0;
            float4 v0 = *(const float4*)src;
            float4 v1 = *(const float4*)(src + 4);
            f16x8 h;
            h[0] = (f16)v0.x; h[1] = (f16)v0.y; h[2] = (f16)v0.z; h[3] = (f16)v0.w;
            h[4] = (f16)v1.x; h[5] = (f16)v1.y; h[6] = (f16)v1.z; h[7] = (f16)v1.w;
            *(f16x8*)&embA[tk * 40 + c0] = h;
        }
        {
            int c0 = (t & 3) * 8;
            int n0 = t >> 2;
#pragma unroll
            for (int rr = 0; rr < 8; rr++) {
                int n = rr * 64 + n0;
                f16x8 v = *(const f16x8*)&bT[n * 512 + kc + c0];
                *(f16x8*)&Bt[n * 40 + c0] = v;
            }
        }
        __syncthreads();

        f16x8 af = *(const f16x8*)&embA[(wv * 16 + lr) * 40 + 8 * lg];
#pragma unroll
        for (int vt = 0; vt < 32; vt++) {
            f16x8 bf = *(const f16x8*)&Bt[(vt * 16 + lr) * 40 + 8 * lg];
            acc[vt] = MFMA16(af, bf, acc[vt]);
        }
    }

    int m0 = wg * 64 + wv * 16 + 4 * lg;
#pragma unroll
    for (int vt = 0; vt < 32; vt++) {
        int n = vt * 16 + lr;
#pragma unroll
        for (int i = 0; i < 4; i++) {
            u16[(size_t)(m0 + i) * NS + n] = (f16)acc[vt][i];
        }
    }
}

// ---------------------------------------------------------------------------
// scan across 4 CUs. Each CU owns NOWN n-columns; A slice fully in registers.
// State broadcast via LDS (rows lr&3) + cross-CU exchange via agent atomics.
// ---------------------------------------------------------------------------
__global__ __launch_bounds__(512) void scan_kernel(
        const float* __restrict__ a, const f16* __restrict__ u16,
        f16* __restrict__ st16, unsigned long long* __restrict__ X,
        unsigned* __restrict__ flags) {
    if (blockIdx.x & 7) return;          // keep bids 0,8,16,24 (XCD-spread hint)
    int r = blockIdx.x >> 3;             // 0..3
    int nown0 = r * NOWN;

    __shared__ f16 Sb[2][4][528];        // [buf][batch][n + pad] : full state

    int t = threadIdx.x;
    int w = t >> 6, l = t & 63, lr = l & 15, lg = l >> 4;
    int nw = nown0 + w * 16;             // this wave's 16-column base

    for (int i = t; i < 2 * 4 * 528; i += 512) ((f16*)Sb)[i] = (f16)0.f;

    // A slice in registers: afr[ks][j] = a[ks*32 + 8*lg + j][nw + lr]
    f16x8 afr[16];
#pragma unroll
    for (int ks = 0; ks < 16; ks++) {
        f16x8 h;
#pragma unroll
        for (int j = 0; j < 8; j++)
            h[j] = (f16)a[(size_t)(ks * 32 + 8 * lg + j) * NS + nw + lr];
        afr[ks] = h;
    }

    // u prefetch for step 0 (lanes lg==0 hold cols nw+lr, batches 0..3)
    float upf[4] = {0.f, 0.f, 0.f, 0.f};
    if (lg == 0) {
#pragma unroll
        for (int b = 0; b < 4; b++)
            upf[b] = (float)u16[(size_t)b * NS + nw + lr];
    }

    __syncthreads();

#pragma unroll 1
    for (int s = 0; s < S_LEN; s++) {
        int cur = s & 1, nxt = cur ^ 1;

        f32x4v acc0, acc1;
        acc0[0] = upf[0]; acc0[1] = upf[1]; acc0[2] = upf[2]; acc0[3] = upf[3];
        acc1 = (f32x4v){0.f, 0.f, 0.f, 0.f};

        // prefetch next step's u (hidden under MFMAs)
        if (lg == 0) {
            int sn = (s + 1 < S_LEN) ? s + 1 : S_LEN - 1;
#pragma unroll
            for (int b = 0; b < 4; b++)
                upf[b] = (float)u16[((size_t)sn * 4 + b) * NS + nw + lr];
        }

        // Y = S @ A, state read with 4-row broadcast (rows lr&3)
        const f16* sb = &Sb[cur][0][0];
        int srow = (lr & 3) * 528 + 8 * lg;
#pragma unroll
        for (int ks = 0; ks < 16; ks += 2) {
            f16x8 s0 = *(const f16x8*)&sb[srow + ks * 32];
            f16x8 s1 = *(const f16x8*)&sb[srow + ks * 32 + 32];
            acc0 = MFMA16(s0, afr[ks], acc0);
            acc1 = MFMA16(s1, afr[ks + 1], acc1);
        }

        // tanh + publish own columns
        if (lg == 0) {
            union { f16 h[4]; unsigned long long u; } pk;
#pragma unroll
            for (int i = 0; i < 4; i++) {
                float y = acc0[i] + acc1[i];
                float ez = __expf(2.f * y);
                y = 1.f - 2.f / (ez + 1.f);           // tanh
                f16 hv = (f16)y;
                pk.h[i] = hv;
                Sb[nxt][i][nw + lr] = hv;
                st16[((size_t)s * 4 + i) * NS + nw + lr] = hv;
            }
            __hip_atomic_store(&X[(size_t)nxt * NS + nw + lr], pk.u,
                               __ATOMIC_RELAXED, __HIP_MEMORY_SCOPE_AGENT);
        }

        if (s == S_LEN - 1) break;

        __syncthreads();   // all X/Sb/st16 writes of this CU drained

        if (t == 0)
            __hip_atomic_store(&flags[r], (unsigned)(s + 1),
                               __ATOMIC_RELEASE, __HIP_MEMORY_SCOPE_AGENT);

        // each wave polls peers independently (no extra barrier needed)
        if (l == 0) {
#pragma unroll
            for (int p = 0; p < NCU; p++) {
                if (p == r) continue;
                while (__hip_atomic_load(&flags[p], __ATOMIC_ACQUIRE,
                                         __HIP_MEMORY_SCOPE_AGENT) <
                       (unsigned)(s + 1))
                    __builtin_amdgcn_s_sleep(1);
            }
        }

        // gather peer columns: thread t handles column n = t
        {
            int n = t;
            if (n < nown0 || n >= nown0 + NOWN) {
                union { f16 h[4]; unsigned long long u; } pk;
                pk.u = __hip_atomic_load(&X[(size_t)nxt * NS + n],
                                         __ATOMIC_RELAXED,
                                         __HIP_MEMORY_SCOPE_AGENT);
#pragma unroll
                for (int b = 0; b < 4; b++) Sb[nxt][b][n] = pk.h[b];
            }
        }

        __syncthreads();   // S_{s+1} complete in Sb[nxt]
    }
}

// ---------------------------------------------------------------------------
// readout: out[b][s][v] = states[s*4+b] . c_w[v] + c_b[v]
// ---------------------------------------------------------------------------
__global__ __launch_bounds__(512) void readout_kernel(
        const f16* __restrict__ st16, const float* __restrict__ cw,
        const float* __restrict__ cb, float* __restrict__ out) {
    __shared__ f16 Ast[256 * 72];
    __shared__ f16 Bw[128 * 72];

    int t = threadIdx.x;
    int bidx = blockIdx.x;
    int bn = bidx % 250;
    int bm = bidx / 250;
    int w = t >> 6, l = t & 63, lr = l & 15, lg = l >> 4;
    int wr = w >> 1, wc = w & 1;

    f32x4v acc[4][4];
#pragma unroll
    for (int i = 0; i < 4; i++)
#pragma unroll
        for (int j = 0; j < 4; j++) acc[i][j] = (f32x4v){0.f, 0.f, 0.f, 0.f};

    for (int kc = 0; kc < 512; kc += 64) {
        __syncthreads();
#pragma unroll
        for (int q = 0; q < 4; q++) {
            int idx = q * 512 + t;
            int row = idx >> 3;
            int c0 = (idx & 7) * 8;
            f16x8 v = *(const f16x8*)&st16[(size_t)(bm * 256 + row) * NS + kc + c0];
            *(f16x8*)&Ast[row * 72 + c0] = v;
        }
#pragma unroll
        for (int q = 0; q < 4; q++) {
            int idx = q * 512 + t;
            int row = idx >> 4;
            int c0 = (idx & 15) * 4;
            float4 v = *(const float4*)&cw[(size_t)(bn * 128 + row) * NS + kc + c0];
            f16x4 h;
            h[0] = (f16)v.x; h[1] = (f16)v.y; h[2] = (f16)v.z; h[3] = (f16)v.w;
            *(f16x4*)&Bw[row * 72 + c0] = h;
        }
        __syncthreads();

#pragma unroll
        for (int ks = 0; ks < 2; ks++) {
            f16x8 af[4], bf[4];
#pragma unroll
            for (int mt = 0; mt < 4; mt++)
                af[mt] = *(const f16x8*)&Ast[(wr * 64 + mt * 16 + lr) * 72 +
                                             ks * 32 + 8 * lg];
#pragma unroll
            for (int vt = 0; vt < 4; vt++)
                bf[vt] = *(const f16x8*)&Bw[(wc * 64 + vt * 16 + lr) * 72 +
                                            ks * 32 + 8 * lg];
#pragma unroll
            for (int mt = 0; mt < 4; mt++)
#pragma unroll
                for (int vt = 0; vt < 4; vt++)
                    acc[mt][vt] = MFMA16(af[mt], bf[vt], acc[mt][vt]);
        }
    }

    float bias[4];
#pragma unroll
    for (int vt = 0; vt < 4; vt++)
        bias[vt] = cb[bn * 128 + wc * 64 + vt * 16 + lr];

#pragma unroll
    for (int mt = 0; mt < 4; mt++) {
#pragma unroll
        for (int i = 0; i < 4; i++) {
            int m = bm * 256 + wr * 64 + mt * 16 + 4 * lg + i;
            int bb = m & 3, ss = m >> 2;
            float* orow = out + (size_t)(bb * S_LEN + ss) * NV + bn * 128 + wc * 64;
#pragma unroll
            for (int vt = 0; vt < 4; vt++)
                orow[vt * 16 + lr] = acc[mt][vt][i] + bias[vt];
        }
    }
}

// ---------------------------------------------------------------------------
extern "C" void kernel_launch(void* const* d_in, const int* in_sizes, int n_in,
                              void* d_out, int out_size, void* d_ws, size_t ws_size,
                              hipStream_t stream) {
    (void)in_sizes; (void)n_in; (void)out_size; (void)ws_size;

    const int*   x   = (const int*)d_in[0];
    const float* emb = (const float*)d_in[1];
    const float* a   = (const float*)d_in[2];
    const float* bm  = (const float*)d_in[3];
    const float* cw  = (const float*)d_in[4];
    const float* cb  = (const float*)d_in[5];
    float* out = (float*)d_out;

    char* ws = (char*)d_ws;
    f16* u16  = (f16*)(ws);
    f16* st16 = (f16*)(ws + (4u << 20));
    f16* bT16 = (f16*)(ws + (8u << 20));
    unsigned* flags = (unsigned*)(ws + (8u << 20) + (512u << 10));
    unsigned long long* X =
        (unsigned long long*)(ws + (8u << 20) + (512u << 10) + 256);

    transpose512_f16_kernel<<<1024, 256, 0, stream>>>(bm, bT16, flags);
    embu_kernel<<<64, 256, 0, stream>>>(x, emb, bT16, u16);
    scan_kernel<<<32, 512, 0, stream>>>(a, u16, st16, X, flags);
    readout_kernel<<<16 * 250, 512, 0, stream>>>(st16, cw, cb, out);
}

// Round 3
// 2992.881 us; speedup vs baseline: 3.1128x; 3.1128x over previous
//
#include <hip/hip_runtime.h>
#include <hip/hip_fp16.h>

typedef _Float16 f16;
typedef _Float16 f16x8 __attribute__((ext_vector_type(8)));
typedef _Float16 f16x4 __attribute__((ext_vector_type(4)));
typedef float f32x4v __attribute__((ext_vector_type(4)));

#define S_LEN 1024
#define NS 512
#define NV 32000

#define MFMA16(a, b, c) __builtin_amdgcn_mfma_f32_16x16x32_f16((a), (b), (c), 0, 0, 0)

// ---------------------------------------------------------------------------
// ws layout:
//   u16   : [1024][512][4] f16  at 0      (4 MB)   u[s][n][b]  (batch-packed)
//   st16  : [1024][4][512] f16  at 4 MB   (4 MB)   states[s][b][n]
//   bT16  : [512][512]     f16  at 8 MB   (512 KB) bT16[n][e] = b[e][n]
// ---------------------------------------------------------------------------

__global__ __launch_bounds__(256) void transpose512_f16_kernel(
        const float* __restrict__ src, f16* __restrict__ dstT) {
    int idx = blockIdx.x * 256 + threadIdx.x;
    int r = idx >> 9;
    int c = idx & 511;
    dstT[c * 512 + r] = (f16)src[idx];
}

// ---------------------------------------------------------------------------
// embed + input projection: u[m][n] = sum_e emb[x[m]][e] * b[e][n], m = s*4+b
// ---------------------------------------------------------------------------
__global__ __launch_bounds__(256) void embu_kernel(
        const int* __restrict__ x, const float* __restrict__ emb,
        const f16* __restrict__ bT, f16* __restrict__ u16) {
    __shared__ f16 embA[64 * 40];
    __shared__ f16 Bt[512 * 40];
    __shared__ int xi[64];

    int t = threadIdx.x;
    int wg = blockIdx.x;
    if (t < 64) {
        int m = wg * 64 + t;
        int bb = m & 3, ss = m >> 2;
        xi[t] = x[bb * S_LEN + ss];
    }
    __syncthreads();

    int wv = t >> 6, l = t & 63, lr = l & 15, lg = l >> 4;

    f32x4v acc[32];
#pragma unroll
    for (int i = 0; i < 32; i++) acc[i] = (f32x4v){0.f, 0.f, 0.f, 0.f};

    for (int kc = 0; kc < 512; kc += 32) {
        __syncthreads();
        {
            int tk = t >> 2, c0 = (t & 3) * 8;
            const float* src = emb + (size_t)xi[tk] * NS + kc + c0;
            float4 v0 = *(const float4*)src;
            float4 v1 = *(const float4*)(src + 4);
            f16x8 h;
            h[0] = (f16)v0.x; h[1] = (f16)v0.y; h[2] = (f16)v0.z; h[3] = (f16)v0.w;
            h[4] = (f16)v1.x; h[5] = (f16)v1.y; h[6] = (f16)v1.z; h[7] = (f16)v1.w;
            *(f16x8*)&embA[tk * 40 + c0] = h;
        }
        {
            int c0 = (t & 3) * 8;
            int n0 = t >> 2;
#pragma unroll
            for (int rr = 0; rr < 8; rr++) {
                int n = rr * 64 + n0;
                f16x8 v = *(const f16x8*)&bT[n * 512 + kc + c0];
                *(f16x8*)&Bt[n * 40 + c0] = v;
            }
        }
        __syncthreads();

        f16x8 af = *(const f16x8*)&embA[(wv * 16 + lr) * 40 + 8 * lg];
#pragma unroll
        for (int vt = 0; vt < 32; vt++) {
            f16x8 bf = *(const f16x8*)&Bt[(vt * 16 + lr) * 40 + 8 * lg];
            acc[vt] = MFMA16(af, bf, acc[vt]);
        }
    }

    // epilogue: m0 multiple of 4 -> batch index = i, seq = m0>>2
    int m0 = wg * 64 + wv * 16 + 4 * lg;
    int ss = m0 >> 2;
#pragma unroll
    for (int vt = 0; vt < 32; vt++) {
        int n = vt * 16 + lr;
        f16x4 h;
#pragma unroll
        for (int i = 0; i < 4; i++) h[i] = (f16)acc[vt][i];
        *(f16x4*)&u16[((size_t)ss * NS + n) * 4] = h;
    }
}

// ---------------------------------------------------------------------------
// scan: single workgroup, 512 threads / 8 waves, one CU.
// s_{t+1} = tanh(s_t @ a + u_t). A k-slices 0..11 in VGPRs, 12..15 in LDS
// (XOR-swizzled [512][128]). State double-buffered in LDS, 1 barrier/step.
// ---------------------------------------------------------------------------
#define SB_STRIDE 544                       // f16; 272 dw == 16 mod 32 -> 2-way max
#define AT_BYTES (512 * 128 * 2)            // 131072
#define SCAN_LDS_BYTES (AT_BYTES + 2 * 4 * SB_STRIDE * 2)   // 139776

__global__ __launch_bounds__(512, 2) void scan_kernel(
        const float* __restrict__ a, const f16* __restrict__ u16,
        f16* __restrict__ st16) {
    extern __shared__ char smem[];
    char* At = smem;                        // [512 n][128 k] f16, XOR-swizzled
    f16* Sb = (f16*)(smem + AT_BYTES);      // [2 buf][4 batch][SB_STRIDE]

    int t = threadIdx.x;
    int w = t >> 6, l = t & 63, lr = l & 15, lg = l >> 4;
    int nbase = w * 64;

    // zero both state buffers
    for (int i = t; i < 2 * 4 * SB_STRIDE; i += 512) Sb[i] = (f16)0.f;

    // stage At: a rows k in [384,512) -> At[n][k-384], byte ^= (n&7)<<4
    for (int i = t; i < 512 * 128; i += 512) {
        int krel = i >> 9;
        int n = i & 511;
        int byte = (n * 256 + krel * 2) ^ ((n & 7) << 4);
        *(f16*)(At + byte) = (f16)a[(size_t)(384 + krel) * NS + n];
    }

    // stationary register fragments: k-slices 0..11
    // afr[tt][ks][j] = a[ks*32 + 8*lg + j][nbase + tt*16 + lr]
    f16x8 afr[4][12];
#pragma unroll
    for (int tt = 0; tt < 4; tt++) {
#pragma unroll
        for (int ks = 0; ks < 12; ks++) {
            f16x8 h;
#pragma unroll
            for (int j = 0; j < 8; j++)
                h[j] = (f16)a[(size_t)(ks * 32 + 8 * lg + j) * NS +
                              nbase + tt * 16 + lr];
            afr[tt][ks] = h;
        }
    }

    // u prefetch for step 0: one 8B load per (lane, tt); only lg==0 rows used
    f16x4 upf[4];
#pragma unroll
    for (int tt = 0; tt < 4; tt++)
        upf[tt] = *(const f16x4*)&u16[((size_t)0 * NS + nbase + tt * 16 + lr) * 4];

    __syncthreads();

    int soff = (lr & 3) * SB_STRIDE + 8 * lg;   // broadcast state read (f16 idx)

#pragma unroll 1
    for (int s = 0; s < S_LEN; s++) {
        int cur = s & 1, nxt = cur ^ 1;
        const f16* sbR = Sb + cur * (4 * SB_STRIDE);
        f16* sbW = Sb + nxt * (4 * SB_STRIDE);

        // init accumulators from u (rows 0..3 valid on lg==0; rest garbage/discarded)
        f32x4v acc[4];
#pragma unroll
        for (int tt = 0; tt < 4; tt++) {
            acc[tt][0] = (float)upf[tt][0];
            acc[tt][1] = (float)upf[tt][1];
            acc[tt][2] = (float)upf[tt][2];
            acc[tt][3] = (float)upf[tt][3];
        }

        // prefetch next step's u (hidden under MFMAs)
        {
            int sn = (s + 1 < S_LEN) ? s + 1 : S_LEN - 1;
#pragma unroll
            for (int tt = 0; tt < 4; tt++)
                upf[tt] = *(const f16x4*)
                    &u16[((size_t)sn * NS + nbase + tt * 16 + lr) * 4];
        }

        // k-slices 0..11 from register fragments
#pragma unroll
        for (int ks = 0; ks < 12; ks++) {
            f16x8 sf = *(const f16x8*)&sbR[soff + ks * 32];
#pragma unroll
            for (int tt = 0; tt < 4; tt++)
                acc[tt] = MFMA16(sf, afr[tt][ks], acc[tt]);
        }
        // k-slices 12..15 from swizzled LDS
#pragma unroll
        for (int ks = 12; ks < 16; ks++) {
            f16x8 sf = *(const f16x8*)&sbR[soff + ks * 32];
#pragma unroll
            for (int tt = 0; tt < 4; tt++) {
                int row = nbase + tt * 16 + lr;
                int byte = (row * 256 + (ks - 12) * 64 + lg * 16) ^
                           ((row & 7) << 4);
                f16x8 bf = *(const f16x8*)(At + byte);
                acc[tt] = MFMA16(sf, bf, acc[tt]);
            }
        }

        // tanh + publish own 64 columns (16 lanes x 4tt x 4 batches)
        if (lg == 0) {
#pragma unroll
            for (int tt = 0; tt < 4; tt++) {
                int n = nbase + tt * 16 + lr;
#pragma unroll
                for (int i = 0; i < 4; i++) {
                    float y = acc[tt][i];
                    float ez = __expf(2.f * y);
                    y = 1.f - 2.f / (ez + 1.f);   // tanh
                    f16 hv = (f16)y;
                    sbW[i * SB_STRIDE + n] = hv;
                    st16[((size_t)s * 4 + i) * NS + n] = hv;
                }
            }
        }

        if (s == S_LEN - 1) break;

        // one raw barrier per step: LDS writes drained, no vmcnt(0) drain
        asm volatile("s_waitcnt lgkmcnt(0)" ::: "memory");
        __builtin_amdgcn_s_barrier();
        asm volatile("" ::: "memory");
    }
}

// ---------------------------------------------------------------------------
// readout: out[b][s][v] = states[s*4+b] . c_w[v] + c_b[v]
// ---------------------------------------------------------------------------
__global__ __launch_bounds__(512) void readout_kernel(
        const f16* __restrict__ st16, const float* __restrict__ cw,
        const float* __restrict__ cb, float* __restrict__ out) {
    __shared__ f16 Ast[256 * 72];
    __shared__ f16 Bw[128 * 72];

    int t = threadIdx.x;
    int bidx = blockIdx.x;
    int bn = bidx % 250;
    int bm = bidx / 250;
    int w = t >> 6, l = t & 63, lr = l & 15, lg = l >> 4;
    int wr = w >> 1, wc = w & 1;

    f32x4v acc[4][4];
#pragma unroll
    for (int i = 0; i < 4; i++)
#pragma unroll
        for (int j = 0; j < 4; j++) acc[i][j] = (f32x4v){0.f, 0.f, 0.f, 0.f};

    for (int kc = 0; kc < 512; kc += 64) {
        __syncthreads();
#pragma unroll
        for (int q = 0; q < 4; q++) {
            int idx = q * 512 + t;
            int row = idx >> 3;
            int c0 = (idx & 7) * 8;
            f16x8 v = *(const f16x8*)&st16[(size_t)(bm * 256 + row) * NS + kc + c0];
            *(f16x8*)&Ast[row * 72 + c0] = v;
        }
#pragma unroll
        for (int q = 0; q < 4; q++) {
            int idx = q * 512 + t;
            int row = idx >> 4;
            int c0 = (idx & 15) * 4;
            float4 v = *(const float4*)&cw[(size_t)(bn * 128 + row) * NS + kc + c0];
            f16x4 h;
            h[0] = (f16)v.x; h[1] = (f16)v.y; h[2] = (f16)v.z; h[3] = (f16)v.w;
            *(f16x4*)&Bw[row * 72 + c0] = h;
        }
        __syncthreads();

#pragma unroll
        for (int ks = 0; ks < 2; ks++) {
            f16x8 af[4], bf[4];
#pragma unroll
            for (int mt = 0; mt < 4; mt++)
                af[mt] = *(const f16x8*)&Ast[(wr * 64 + mt * 16 + lr) * 72 +
                                             ks * 32 + 8 * lg];
#pragma unroll
            for (int vt = 0; vt < 4; vt++)
                bf[vt] = *(const f16x8*)&Bw[(wc * 64 + vt * 16 + lr) * 72 +
                                            ks * 32 + 8 * lg];
#pragma unroll
            for (int mt = 0; mt < 4; mt++)
#pragma unroll
                for (int vt = 0; vt < 4; vt++)
                    acc[mt][vt] = MFMA16(af[mt], bf[vt], acc[mt][vt]);
        }
    }

    float bias[4];
#pragma unroll
    for (int vt = 0; vt < 4; vt++)
        bias[vt] = cb[bn * 128 + wc * 64 + vt * 16 + lr];

#pragma unroll
    for (int mt = 0; mt < 4; mt++) {
#pragma unroll
        for (int i = 0; i < 4; i++) {
            int m = bm * 256 + wr * 64 + mt * 16 + 4 * lg + i;
            int bb = m & 3, ss = m >> 2;
            float* orow = out + (size_t)(bb * S_LEN + ss) * NV + bn * 128 + wc * 64;
#pragma unroll
            for (int vt = 0; vt < 4; vt++)
                orow[vt * 16 + lr] = acc[mt][vt][i] + bias[vt];
        }
    }
}

// ---------------------------------------------------------------------------
extern "C" void kernel_launch(void* const* d_in, const int* in_sizes, int n_in,
                              void* d_out, int out_size, void* d_ws, size_t ws_size,
                              hipStream_t stream) {
    (void)in_sizes; (void)n_in; (void)out_size; (void)ws_size;

    const int*   x   = (const int*)d_in[0];
    const float* emb = (const float*)d_in[1];
    const float* a   = (const float*)d_in[2];
    const float* bm  = (const float*)d_in[3];
    const float* cw  = (const float*)d_in[4];
    const float* cb  = (const float*)d_in[5];
    float* out = (float*)d_out;

    char* ws = (char*)d_ws;
    f16* u16  = (f16*)(ws);
    f16* st16 = (f16*)(ws + (4u << 20));
    f16* bT16 = (f16*)(ws + (8u << 20));

    hipFuncSetAttribute(reinterpret_cast<const void*>(scan_kernel),
                        hipFuncAttributeMaxDynamicSharedMemorySize,
                        SCAN_LDS_BYTES);

    transpose512_f16_kernel<<<1024, 256, 0, stream>>>(bm, bT16);
    embu_kernel<<<64, 256, 0, stream>>>(x, emb, bT16, u16);
    scan_kernel<<<1, 512, SCAN_LDS_BYTES, stream>>>(a, u16, st16);
    readout_kernel<<<16 * 250, 512, 0, stream>>>(st16, cw, cb, out);
}

// Round 4
// 2290.954 us; speedup vs baseline: 4.0665x; 1.3064x over previous
//
#include <hip/hip_runtime.h>
#include <hip/hip_fp16.h>

typedef _Float16 f16;
typedef _Float16 f16x8 __attribute__((ext_vector_type(8)));
typedef _Float16 f16x4 __attribute__((ext_vector_type(4)));
typedef float f32x4v __attribute__((ext_vector_type(4)));

#define S_LEN 1024
#define NS 512
#define NV 32000

#define MFMA16(a, b, c) __builtin_amdgcn_mfma_f32_16x16x32_f16((a), (b), (c), 0, 0, 0)

// ---------------------------------------------------------------------------
// ws layout:
//   u16   : [1024][512][4] f16  at 0      (4 MB)   u[s][n][b]  (batch-packed)
//   st16  : [1024][4][512] f16  at 4 MB   (4 MB)   states[s][b][n]
//   bT16  : [512][512]     f16  at 8 MB   (512 KB) bT16[n][e] = b[e][n]
// ---------------------------------------------------------------------------

__global__ __launch_bounds__(256) void transpose512_f16_kernel(
        const float* __restrict__ src, f16* __restrict__ dstT) {
    int idx = blockIdx.x * 256 + threadIdx.x;
    int r = idx >> 9;
    int c = idx & 511;
    dstT[c * 512 + r] = (f16)src[idx];
}

// ---------------------------------------------------------------------------
// embed + input projection: u[m][n] = sum_e emb[x[m]][e] * b[e][n], m = s*4+b
// ---------------------------------------------------------------------------
__global__ __launch_bounds__(256) void embu_kernel(
        const int* __restrict__ x, const float* __restrict__ emb,
        const f16* __restrict__ bT, f16* __restrict__ u16) {
    __shared__ f16 embA[64 * 40];
    __shared__ f16 Bt[512 * 40];
    __shared__ int xi[64];

    int t = threadIdx.x;
    int wg = blockIdx.x;
    if (t < 64) {
        int m = wg * 64 + t;
        int bb = m & 3, ss = m >> 2;
        xi[t] = x[bb * S_LEN + ss];
    }
    __syncthreads();

    int wv = t >> 6, l = t & 63, lr = l & 15, lg = l >> 4;

    f32x4v acc[32];
#pragma unroll
    for (int i = 0; i < 32; i++) acc[i] = (f32x4v){0.f, 0.f, 0.f, 0.f};

    for (int kc = 0; kc < 512; kc += 32) {
        __syncthreads();
        {
            int tk = t >> 2, c0 = (t & 3) * 8;
            const float* src = emb + (size_t)xi[tk] * NS + kc + c0;
            float4 v0 = *(const float4*)src;
            float4 v1 = *(const float4*)(src + 4);
            f16x8 h;
            h[0] = (f16)v0.x; h[1] = (f16)v0.y; h[2] = (f16)v0.z; h[3] = (f16)v0.w;
            h[4] = (f16)v1.x; h[5] = (f16)v1.y; h[6] = (f16)v1.z; h[7] = (f16)v1.w;
            *(f16x8*)&embA[tk * 40 + c0] = h;
        }
        {
            int c0 = (t & 3) * 8;
            int n0 = t >> 2;
#pragma unroll
            for (int rr = 0; rr < 8; rr++) {
                int n = rr * 64 + n0;
                f16x8 v = *(const f16x8*)&bT[n * 512 + kc + c0];
                *(f16x8*)&Bt[n * 40 + c0] = v;
            }
        }
        __syncthreads();

        f16x8 af = *(const f16x8*)&embA[(wv * 16 + lr) * 40 + 8 * lg];
#pragma unroll
        for (int vt = 0; vt < 32; vt++) {
            f16x8 bf = *(const f16x8*)&Bt[(vt * 16 + lr) * 40 + 8 * lg];
            acc[vt] = MFMA16(af, bf, acc[vt]);
        }
    }

    int m0 = wg * 64 + wv * 16 + 4 * lg;
    int ss = m0 >> 2;
#pragma unroll
    for (int vt = 0; vt < 32; vt++) {
        int n = vt * 16 + lr;
        f16x4 h;
#pragma unroll
        for (int i = 0; i < 4; i++) h[i] = (f16)acc[vt][i];
        *(f16x4*)&u16[((size_t)ss * NS + n) * 4] = h;
    }
}

// ---------------------------------------------------------------------------
// scan: single workgroup, 512 threads / 8 waves, one CU.
// s_{t+1} = tanh(s_t @ a + u_t). A k-slices 0..11 in VGPRs (192 regs),
// 12..15 in XOR-swizzled LDS. State double-buffered in LDS, 1 barrier/step.
// All per-step LDS addressing = base VGPR + compile-time immediate.
// ---------------------------------------------------------------------------
#define SB_STRIDE 544                       // f16; row stride
#define AT_BYTES (512 * 128 * 2)            // 131072
#define SB_BUFBYTES (4 * SB_STRIDE * 2)     // 4352
#define SCAN_LDS_BYTES (AT_BYTES + 2 * SB_BUFBYTES)   // 139776

__global__ __launch_bounds__(512, 1) void scan_kernel(
        const float* __restrict__ a, const f16* __restrict__ u16,
        f16* __restrict__ st16) {
    extern __shared__ char smem[];
    char* At = smem;                        // [512 n][128 k] f16, XOR-swizzled
    f16* Sb = (f16*)(smem + AT_BYTES);      // [2 buf][4 batch][SB_STRIDE]

    int t = threadIdx.x;
    int w = t >> 6, l = t & 63, lr = l & 15, lg = l >> 4;
    int nbase = w * 64;

    // zero both state buffers
    for (int i = t; i < 2 * 4 * SB_STRIDE; i += 512) Sb[i] = (f16)0.f;

    // stage At: a rows k in [384,512) -> At[n][k-384], byte ^= (n&7)<<4
    for (int i = t; i < 512 * 128; i += 512) {
        int krel = i >> 9;
        int n = i & 511;
        int byte = (n * 256 + krel * 2) ^ ((n & 7) << 4);
        *(f16*)(At + byte) = (f16)a[(size_t)(384 + krel) * NS + n];
    }

    // stationary register fragments: k-slices 0..11 (192 VGPRs)
    f16x8 afr[4][12];
#pragma unroll
    for (int tt = 0; tt < 4; tt++) {
#pragma unroll
        for (int ks = 0; ks < 12; ks++) {
            f16x8 h;
#pragma unroll
            for (int j = 0; j < 8; j++)
                h[j] = (f16)a[(size_t)(ks * 32 + 8 * lg + j) * NS +
                              nbase + tt * 16 + lr];
            afr[tt][ks] = h;
        }
    }

    // u prefetch for step 0
    f16x4 upf[4];
#pragma unroll
    for (int tt = 0; tt < 4; tt++)
        upf[tt] = *(const f16x4*)&u16[((size_t)0 * NS + nbase + tt * 16 + lr) * 4];

    __syncthreads();

    // ---- precomputed bases (all per-step accesses = base + imm) ----
    const char* sbR0 = (const char*)Sb + ((lr & 3) * SB_STRIDE + 8 * lg) * 2;
    const char* sbR1 = sbR0 + SB_BUFBYTES;
    char* sbW0 = (char*)Sb + (nbase + lr) * 2;          // + i*1088 + tt*32 imm
    char* sbW1 = sbW0 + SB_BUFBYTES;
    const char* atBev =
        At + ((((nbase + lr) * 256) + lg * 16) ^ ((lr & 7) << 4));
    const char* atBod =
        At + ((((nbase + lr) * 256) + 64 + lg * 16) ^ ((lr & 7) << 4));
    const int stoff = nbase + lr;                       // st16 column base

#define SCAN_STEP(S, SBR, SBW)                                               \
    {                                                                        \
        f32x4v acc[4];                                                       \
        _Pragma("unroll") for (int tt = 0; tt < 4; tt++) {                   \
            acc[tt][0] = (float)upf[tt][0];                                  \
            acc[tt][1] = (float)upf[tt][1];                                  \
            acc[tt][2] = (float)upf[tt][2];                                  \
            acc[tt][3] = (float)upf[tt][3];                                  \
        }                                                                    \
        {                                                                    \
            int sn = ((S) + 1 < S_LEN) ? (S) + 1 : S_LEN - 1;                \
            const f16* ub = u16 + (size_t)sn * (NS * 4);                     \
            _Pragma("unroll") for (int tt = 0; tt < 4; tt++)                 \
                upf[tt] = *(const f16x4*)&ub[(stoff + tt * 16) * 4];         \
        }                                                                    \
        _Pragma("unroll") for (int ks = 0; ks < 12; ks++) {                  \
            f16x8 sf = *(const f16x8*)((SBR) + ks * 64);                     \
            _Pragma("unroll") for (int tt = 0; tt < 4; tt++)                 \
                acc[tt] = MFMA16(sf, afr[tt][ks], acc[tt]);                  \
        }                                                                    \
        _Pragma("unroll") for (int kq = 0; kq < 4; kq++) {                   \
            f16x8 sf = *(const f16x8*)((SBR) + (12 + kq) * 64);              \
            const char* ab = (kq & 1) ? atBod : atBev;                       \
            const int koff = (kq >> 1) * 128;                                \
            _Pragma("unroll") for (int tt = 0; tt < 4; tt++) {               \
                f16x8 bf = *(const f16x8*)(ab + koff + tt * 4096);           \
                acc[tt] = MFMA16(sf, bf, acc[tt]);                           \
            }                                                                \
        }                                                                    \
        if (lg == 0) {                                                       \
            _Pragma("unroll") for (int tt = 0; tt < 4; tt++) {               \
                _Pragma("unroll") for (int i = 0; i < 4; i++) {              \
                    float y = acc[tt][i];                                    \
                    float e = __expf(2.0f * y);                              \
                    float rc = __builtin_amdgcn_rcpf(e + 1.0f);              \
                    y = __builtin_fmaf(-2.0f, rc, 1.0f);                     \
                    f16 hv = (f16)y;                                         \
                    *(f16*)((SBW) + i * (SB_STRIDE * 2) + tt * 32) = hv;     \
                    st16[((size_t)(S) * 4 + i) * NS + stoff + tt * 16] = hv; \
                }                                                            \
            }                                                                \
        }                                                                    \
    }

#define SCAN_BARRIER()                                                       \
    asm volatile("s_waitcnt lgkmcnt(0)" ::: "memory");                       \
    __builtin_amdgcn_s_barrier();                                            \
    __builtin_amdgcn_sched_barrier(0);

#pragma unroll 1
    for (int s2 = 0; s2 < S_LEN; s2 += 2) {
        SCAN_STEP(s2, sbR0, sbW1);
        SCAN_BARRIER();
        SCAN_STEP(s2 + 1, sbR1, sbW0);
        if (s2 + 2 < S_LEN) { SCAN_BARRIER(); }
    }
#undef SCAN_STEP
#undef SCAN_BARRIER
}

// ---------------------------------------------------------------------------
// readout: out[b][s][v] = states[s*4+b] . c_w[v] + c_b[v]
// ---------------------------------------------------------------------------
__global__ __launch_bounds__(512) void readout_kernel(
        const f16* __restrict__ st16, const float* __restrict__ cw,
        const float* __restrict__ cb, float* __restrict__ out) {
    __shared__ f16 Ast[256 * 72];
    __shared__ f16 Bw[128 * 72];

    int t = threadIdx.x;
    int bidx = blockIdx.x;
    int bn = bidx % 250;
    int bm = bidx / 250;
    int w = t >> 6, l = t & 63, lr = l & 15, lg = l >> 4;
    int wr = w >> 1, wc = w & 1;

    f32x4v acc[4][4];
#pragma unroll
    for (int i = 0; i < 4; i++)
#pragma unroll
        for (int j = 0; j < 4; j++) acc[i][j] = (f32x4v){0.f, 0.f, 0.f, 0.f};

    for (int kc = 0; kc < 512; kc += 64) {
        __syncthreads();
#pragma unroll
        for (int q = 0; q < 4; q++) {
            int idx = q * 512 + t;
            int row = idx >> 3;
            int c0 = (idx & 7) * 8;
            f16x8 v = *(const f16x8*)&st16[(size_t)(bm * 256 + row) * NS + kc + c0];
            *(f16x8*)&Ast[row * 72 + c0] = v;
        }
#pragma unroll
        for (int q = 0; q < 4; q++) {
            int idx = q * 512 + t;
            int row = idx >> 4;
            int c0 = (idx & 15) * 4;
            float4 v = *(const float4*)&cw[(size_t)(bn * 128 + row) * NS + kc + c0];
            f16x4 h;
            h[0] = (f16)v.x; h[1] = (f16)v.y; h[2] = (f16)v.z; h[3] = (f16)v.w;
            *(f16x4*)&Bw[row * 72 + c0] = h;
        }
        __syncthreads();

#pragma unroll
        for (int ks = 0; ks < 2; ks++) {
            f16x8 af[4], bf[4];
#pragma unroll
            for (int mt = 0; mt < 4; mt++)
                af[mt] = *(const f16x8*)&Ast[(wr * 64 + mt * 16 + lr) * 72 +
                                             ks * 32 + 8 * lg];
#pragma unroll
            for (int vt = 0; vt < 4; vt++)
                bf[vt] = *(const f16x8*)&Bw[(wc * 64 + vt * 16 + lr) * 72 +
                                            ks * 32 + 8 * lg];
#pragma unroll
            for (int mt = 0; mt < 4; mt++)
#pragma unroll
                for (int vt = 0; vt < 4; vt++)
                    acc[mt][vt] = MFMA16(af[mt], bf[vt], acc[mt][vt]);
        }
    }

    float bias[4];
#pragma unroll
    for (int vt = 0; vt < 4; vt++)
        bias[vt] = cb[bn * 128 + wc * 64 + vt * 16 + lr];

#pragma unroll
    for (int mt = 0; mt < 4; mt++) {
#pragma unroll
        for (int i = 0; i < 4; i++) {
            int m = bm * 256 + wr * 64 + mt * 16 + 4 * lg + i;
            int bb = m & 3, ss = m >> 2;
            float* orow = out + (size_t)(bb * S_LEN + ss) * NV + bn * 128 + wc * 64;
#pragma unroll
            for (int vt = 0; vt < 4; vt++)
                orow[vt * 16 + lr] = acc[mt][vt][i] + bias[vt];
        }
    }
}

// ---------------------------------------------------------------------------
extern "C" void kernel_launch(void* const* d_in, const int* in_sizes, int n_in,
                              void* d_out, int out_size, void* d_ws, size_t ws_size,
                              hipStream_t stream) {
    (void)in_sizes; (void)n_in; (void)out_size; (void)ws_size;

    const int*   x   = (const int*)d_in[0];
    const float* emb = (const float*)d_in[1];
    const float* a   = (const float*)d_in[2];
    const float* bm  = (const float*)d_in[3];
    const float* cw  = (const float*)d_in[4];
    const float* cb  = (const float*)d_in[5];
    float* out = (float*)d_out;

    char* ws = (char*)d_ws;
    f16* u16  = (f16*)(ws);
    f16* st16 = (f16*)(ws + (4u << 20));
    f16* bT16 = (f16*)(ws + (8u << 20));

    hipFuncSetAttribute(reinterpret_cast<const void*>(scan_kernel),
                        hipFuncAttributeMaxDynamicSharedMemorySize,
                        SCAN_LDS_BYTES);

    transpose512_f16_kernel<<<1024, 256, 0, stream>>>(bm, bT16);
    embu_kernel<<<64, 256, 0, stream>>>(x, emb, bT16, u16);
    scan_kernel<<<1, 512, SCAN_LDS_BYTES, stream>>>(a, u16, st16);
    readout_kernel<<<16 * 250, 512, 0, stream>>>(st16, cw, cb, out);
}

// Round 5
// 2280.082 us; speedup vs baseline: 4.0859x; 1.0048x over previous
//
#include <hip/hip_runtime.h>
#include <hip/hip_fp16.h>

typedef _Float16 f16;
typedef _Float16 f16x8 __attribute__((ext_vector_type(8)));
typedef _Float16 f16x4 __attribute__((ext_vector_type(4)));
typedef float f32x4v __attribute__((ext_vector_type(4)));

#define S_LEN 1024
#define NS 512
#define NV 32000
#define NW 4          // workers (CUs) in the scan

#define MFMA16(a, b, c) __builtin_amdgcn_mfma_f32_16x16x32_f16((a), (b), (c), 0, 0, 0)

// ---------------------------------------------------------------------------
// ws layout:
//   u16   : [1024][512][4] f16  at 0      (4 MB)   u[s][n][b]  (batch-packed)
//   st16  : [1024][4][512] f16  at 4 MB   (4 MB)   states[s][b][n]
//   X     : u64[1024][512]      at 8 MB   (4 MB)   packed state exchange
//   bT16  : [512][512]     f16  at 12 MB  (512 KB)
//   flags : u32[8]              at 12.5MB          (zeroed every launch)
// ---------------------------------------------------------------------------

__global__ __launch_bounds__(256) void transpose512_f16_kernel(
        const float* __restrict__ src, f16* __restrict__ dstT,
        unsigned* __restrict__ flags) {
    int idx = blockIdx.x * 256 + threadIdx.x;
    if (idx < 8) flags[idx] = 0;   // reset scan sync flags (graph-replay safe)
    int r = idx >> 9;
    int c = idx & 511;
    dstT[c * 512 + r] = (f16)src[idx];
}

// ---------------------------------------------------------------------------
// embed + input projection: u[m][n] = sum_e emb[x[m]][e] * b[e][n], m = s*4+b
// ---------------------------------------------------------------------------
__global__ __launch_bounds__(256) void embu_kernel(
        const int* __restrict__ x, const float* __restrict__ emb,
        const f16* __restrict__ bT, f16* __restrict__ u16) {
    __shared__ f16 embA[64 * 40];
    __shared__ f16 Bt[512 * 40];
    __shared__ int xi[64];

    int t = threadIdx.x;
    int wg = blockIdx.x;
    if (t < 64) {
        int m = wg * 64 + t;
        int bb = m & 3, ss = m >> 2;
        xi[t] = x[bb * S_LEN + ss];
    }
    __syncthreads();

    int wv = t >> 6, l = t & 63, lr = l & 15, lg = l >> 4;

    f32x4v acc[32];
#pragma unroll
    for (int i = 0; i < 32; i++) acc[i] = (f32x4v){0.f, 0.f, 0.f, 0.f};

    for (int kc = 0; kc < 512; kc += 32) {
        __syncthreads();
        {
            int tk = t >> 2, c0 = (t & 3) * 8;
            const float* src = emb + (size_t)xi[tk] * NS + kc + c0;
            float4 v0 = *(const float4*)src;
            float4 v1 = *(const float4*)(src + 4);
            f16x8 h;
            h[0] = (f16)v0.x; h[1] = (f16)v0.y; h[2] = (f16)v0.z; h[3] = (f16)v0.w;
            h[4] = (f16)v1.x; h[5] = (f16)v1.y; h[6] = (f16)v1.z; h[7] = (f16)v1.w;
            *(f16x8*)&embA[tk * 40 + c0] = h;
        }
        {
            int c0 = (t & 3) * 8;
            int n0 = t >> 2;
#pragma unroll
            for (int rr = 0; rr < 8; rr++) {
                int n = rr * 64 + n0;
                f16x8 v = *(const f16x8*)&bT[n * 512 + kc + c0];
                *(f16x8*)&Bt[n * 40 + c0] = v;
            }
        }
        __syncthreads();

        f16x8 af = *(const f16x8*)&embA[(wv * 16 + lr) * 40 + 8 * lg];
#pragma unroll
        for (int vt = 0; vt < 32; vt++) {
            f16x8 bf = *(const f16x8*)&Bt[(vt * 16 + lr) * 40 + 8 * lg];
            acc[vt] = MFMA16(af, bf, acc[vt]);
        }
    }

    int m0 = wg * 64 + wv * 16 + 4 * lg;
    int ss = m0 >> 2;
#pragma unroll
    for (int vt = 0; vt < 32; vt++) {
        int n = vt * 16 + lr;
        f16x4 h;
#pragma unroll
        for (int i = 0; i < 4; i++) h[i] = (f16)acc[vt][i];
        *(f16x4*)&u16[((size_t)ss * NS + n) * 4] = h;
    }
}

// ---------------------------------------------------------------------------
// scan on 4 CUs (blocks 0..3). Each CU owns 128 n-columns; its A-slice is
// fully register-resident (16 fragments = 64 VGPRs/lane). Cross-CU state
// exchange via RELAXED agent-scope atomics (sc0/sc1, LLC-routed, no
// fences/cache flushes) + monotone per-worker step flags.
// ---------------------------------------------------------------------------
__global__ __launch_bounds__(512) void scan_kernel(
        const float* __restrict__ a, const f16* __restrict__ u16,
        f16* __restrict__ st16, unsigned long long* __restrict__ X,
        unsigned* __restrict__ flags) {
    __shared__ f16 Sb[2][4][544];   // [buf][batch][col(+pad)] full 512-state

    int t = threadIdx.x;
    int r = blockIdx.x;                 // worker rank 0..3
    int w = t >> 6, l = t & 63, lr = l & 15, lg = l >> 4;
    int col = r * 128 + w * 16 + lr;    // this lane's output column

    // zero both state buffers
    for (int i = t; i < 2 * 4 * 544; i += 512) ((f16*)Sb)[i] = (f16)0.f;

    // stationary A fragments: afr[ks][j] = a[ks*32 + 8*lg + j][col]  (64 VGPR)
    f16x8 afr[16];
#pragma unroll
    for (int ks = 0; ks < 16; ks++) {
        f16x8 h;
#pragma unroll
        for (int j = 0; j < 8; j++)
            h[j] = (f16)a[(size_t)(ks * 32 + 8 * lg + j) * NS + col];
        afr[ks] = h;
    }

    // u prefetch for step 0 (batch-packed u64 per column)
    f16x4 upf = *(const f16x4*)&u16[(size_t)col * 4];

    __syncthreads();

#pragma unroll 1
    for (int s = 0; s < S_LEN; s++) {
        int cur = s & 1, nxt = cur ^ 1;

        f32x4v acca, accb;
        acca[0] = (float)upf[0]; acca[1] = (float)upf[1];
        acca[2] = (float)upf[2]; acca[3] = (float)upf[3];
        accb = (f32x4v){0.f, 0.f, 0.f, 0.f};

        // prefetch next step's u (hidden under MFMAs)
        {
            int sn = (s + 1 < S_LEN) ? s + 1 : S_LEN - 1;
            upf = *(const f16x4*)&u16[((size_t)sn * NS + col) * 4];
        }

        // Y = S @ A : 16 k-slices, state from LDS (4-row broadcast), A in regs
        const char* sb = (const char*)Sb + cur * 4352 + (lr & 3) * 1088 + lg * 16;
#pragma unroll
        for (int ks = 0; ks < 16; ks += 2) {
            f16x8 s0 = *(const f16x8*)(sb + ks * 64);
            f16x8 s1 = *(const f16x8*)(sb + ks * 64 + 64);
            acca = MFMA16(s0, afr[ks], acca);
            accb = MFMA16(s1, afr[ks + 1], accb);
        }

        // tanh + publish own 16-col tile (lanes 0..15 hold all 4 batches)
        if (lg == 0) {
            union { unsigned long long u; f16 h[4]; } pk;
#pragma unroll
            for (int i = 0; i < 4; i++) {
                float y = acca[i] + accb[i];
                float e = __expf(2.0f * y);
                float rc = __builtin_amdgcn_rcpf(e + 1.0f);
                y = __builtin_fmaf(-2.0f, rc, 1.0f);   // tanh
                pk.h[i] = (f16)y;
            }
            __builtin_amdgcn_sched_barrier(0);
            // X first (covered by vmcnt(4)); relaxed agent atomic -> sc0 sc1
            __hip_atomic_store(&X[(size_t)s * NS + col], pk.u,
                               __ATOMIC_RELAXED, __HIP_MEMORY_SCOPE_AGENT);
            __builtin_amdgcn_sched_barrier(0);
#pragma unroll
            for (int i = 0; i < 4; i++) {
                Sb[nxt][i][col] = pk.h[i];
                st16[((size_t)s * 4 + i) * NS + col] = pk.h[i];
            }
        }

        if (s == S_LEN - 1) break;

        // wait until upf + X store retired (4 st16 stores may stay in flight)
        asm volatile("s_waitcnt vmcnt(4) lgkmcnt(0)" ::: "memory");
        __builtin_amdgcn_s_barrier();               // A: all waves' X visible
        __builtin_amdgcn_sched_barrier(0);

        if (t == 0)
            __hip_atomic_store(&flags[r], (unsigned)(s + 1),
                               __ATOMIC_RELAXED, __HIP_MEMORY_SCOPE_AGENT);

        // waves 0..2 poll + gather one peer each (128 cols = 2 u64/lane)
        if (w < 3) {
            int p = w + (w >= r ? 1 : 0);
            while (__hip_atomic_load(&flags[p], __ATOMIC_RELAXED,
                                     __HIP_MEMORY_SCOPE_AGENT) <
                   (unsigned)(s + 1))
                __builtin_amdgcn_s_sleep(1);
            __builtin_amdgcn_sched_barrier(0);
            const unsigned long long* xs = X + (size_t)s * NS + p * 128;
#pragma unroll
            for (int it = 0; it < 2; it++) {
                union { unsigned long long u; f16 h[4]; } pk;
                pk.u = __hip_atomic_load(&xs[it * 64 + l], __ATOMIC_RELAXED,
                                         __HIP_MEMORY_SCOPE_AGENT);
                int gc = p * 128 + it * 64 + l;
#pragma unroll
                for (int i = 0; i < 4; i++) Sb[nxt][i][gc] = pk.h[i];
            }
        }

        asm volatile("s_waitcnt lgkmcnt(0)" ::: "memory");
        __builtin_amdgcn_s_barrier();               // B: S_{s+1} complete
        __builtin_amdgcn_sched_barrier(0);
    }
}

// ---------------------------------------------------------------------------
// readout: out[b][s][v] = states[s*4+b] . c_w[v] + c_b[v]
// ---------------------------------------------------------------------------
__global__ __launch_bounds__(512) void readout_kernel(
        const f16* __restrict__ st16, const float* __restrict__ cw,
        const float* __restrict__ cb, float* __restrict__ out) {
    __shared__ f16 Ast[256 * 72];
    __shared__ f16 Bw[128 * 72];

    int t = threadIdx.x;
    int bidx = blockIdx.x;
    int bn = bidx % 250;
    int bm = bidx / 250;
    int w = t >> 6, l = t & 63, lr = l & 15, lg = l >> 4;
    int wr = w >> 1, wc = w & 1;

    f32x4v acc[4][4];
#pragma unroll
    for (int i = 0; i < 4; i++)
#pragma unroll
        for (int j = 0; j < 4; j++) acc[i][j] = (f32x4v){0.f, 0.f, 0.f, 0.f};

    for (int kc = 0; kc < 512; kc += 64) {
        __syncthreads();
#pragma unroll
        for (int q = 0; q < 4; q++) {
            int idx = q * 512 + t;
            int row = idx >> 3;
            int c0 = (idx & 7) * 8;
            f16x8 v = *(const f16x8*)&st16[(size_t)(bm * 256 + row) * NS + kc + c0];
            *(f16x8*)&Ast[row * 72 + c0] = v;
        }
#pragma unroll
        for (int q = 0; q < 4; q++) {
            int idx = q * 512 + t;
            int row = idx >> 4;
            int c0 = (idx & 15) * 4;
            float4 v = *(const float4*)&cw[(size_t)(bn * 128 + row) * NS + kc + c0];
            f16x4 h;
            h[0] = (f16)v.x; h[1] = (f16)v.y; h[2] = (f16)v.z; h[3] = (f16)v.w;
            *(f16x4*)&Bw[row * 72 + c0] = h;
        }
        __syncthreads();

#pragma unroll
        for (int ks = 0; ks < 2; ks++) {
            f16x8 af[4], bf[4];
#pragma unroll
            for (int mt = 0; mt < 4; mt++)
                af[mt] = *(const f16x8*)&Ast[(wr * 64 + mt * 16 + lr) * 72 +
                                             ks * 32 + 8 * lg];
#pragma unroll
            for (int vt = 0; vt < 4; vt++)
                bf[vt] = *(const f16x8*)&Bw[(wc * 64 + vt * 16 + lr) * 72 +
                                            ks * 32 + 8 * lg];
#pragma unroll
            for (int mt = 0; mt < 4; mt++)
#pragma unroll
                for (int vt = 0; vt < 4; vt++)
                    acc[mt][vt] = MFMA16(af[mt], bf[vt], acc[mt][vt]);
        }
    }

    float bias[4];
#pragma unroll
    for (int vt = 0; vt < 4; vt++)
        bias[vt] = cb[bn * 128 + wc * 64 + vt * 16 + lr];

#pragma unroll
    for (int mt = 0; mt < 4; mt++) {
#pragma unroll
        for (int i = 0; i < 4; i++) {
            int m = bm * 256 + wr * 64 + mt * 16 + 4 * lg + i;
            int bb = m & 3, ss = m >> 2;
            float* orow = out + (size_t)(bb * S_LEN + ss) * NV + bn * 128 + wc * 64;
#pragma unroll
            for (int vt = 0; vt < 4; vt++)
                orow[vt * 16 + lr] = acc[mt][vt][i] + bias[vt];
        }
    }
}

// ---------------------------------------------------------------------------
extern "C" void kernel_launch(void* const* d_in, const int* in_sizes, int n_in,
                              void* d_out, int out_size, void* d_ws, size_t ws_size,
                              hipStream_t stream) {
    (void)in_sizes; (void)n_in; (void)out_size; (void)ws_size;

    const int*   x   = (const int*)d_in[0];
    const float* emb = (const float*)d_in[1];
    const float* a   = (const float*)d_in[2];
    const float* bm  = (const float*)d_in[3];
    const float* cw  = (const float*)d_in[4];
    const float* cb  = (const float*)d_in[5];
    float* out = (float*)d_out;

    char* ws = (char*)d_ws;
    f16* u16  = (f16*)(ws);
    f16* st16 = (f16*)(ws + (4u << 20));
    unsigned long long* X = (unsigned long long*)(ws + (8u << 20));
    f16* bT16 = (f16*)(ws + (12u << 20));
    unsigned* flags = (unsigned*)(ws + (12u << 20) + (512u << 10));

    transpose512_f16_kernel<<<1024, 256, 0, stream>>>(bm, bT16, flags);
    embu_kernel<<<64, 256, 0, stream>>>(x, emb, bT16, u16);
    scan_kernel<<<NW, 512, 0, stream>>>(a, u16, st16, X, flags);
    readout_kernel<<<16 * 250, 512, 0, stream>>>(st16, cw, cb, out);
}

// Round 6
// 1498.390 us; speedup vs baseline: 6.2175x; 1.5217x over previous
//
#include <hip/hip_runtime.h>
#include <hip/hip_fp16.h>

typedef _Float16 f16;
typedef _Float16 f16x8 __attribute__((ext_vector_type(8)));
typedef _Float16 f16x4 __attribute__((ext_vector_type(4)));
typedef float f32x4v __attribute__((ext_vector_type(4)));

#define S_LEN 1024
#define NS 512
#define NV 32000
#define NW 4          // workers (CUs) in the scan
#define SENT 0x7C007C007C007C00ULL   // 4x f16 +inf: unreachable for tanh output

#define MFMA16(a, b, c) __builtin_amdgcn_mfma_f32_16x16x32_f16((a), (b), (c), 0, 0, 0)

// ---------------------------------------------------------------------------
// ws layout:
//   u16   : [1024][512][4] f16  at 0      (4 MB)   u[s][n][b]  (batch-packed)
//   st16  : [1024][4][512] f16  at 4 MB   (4 MB)   states[s][b][n]
//   X     : u64[1024][512]      at 8 MB   (4 MB)   packed state exchange
//   bT16  : [512][512]     f16  at 12 MB  (512 KB)
// ---------------------------------------------------------------------------

// transpose b -> f16, and refill X with sentinel (every launch; graph-safe)
__global__ __launch_bounds__(256) void transpose512_f16_kernel(
        const float* __restrict__ src, f16* __restrict__ dstT,
        unsigned long long* __restrict__ X) {
    int idx = blockIdx.x * 256 + threadIdx.x;   // 0..262143
    X[idx] = SENT;
    X[idx + 262144] = SENT;
    int r = idx >> 9;
    int c = idx & 511;
    dstT[c * 512 + r] = (f16)src[idx];
}

// ---------------------------------------------------------------------------
// embed + input projection: u[m][n] = sum_e emb[x[m]][e] * b[e][n], m = s*4+b
// ---------------------------------------------------------------------------
__global__ __launch_bounds__(256) void embu_kernel(
        const int* __restrict__ x, const float* __restrict__ emb,
        const f16* __restrict__ bT, f16* __restrict__ u16) {
    __shared__ f16 embA[64 * 40];
    __shared__ f16 Bt[512 * 40];
    __shared__ int xi[64];

    int t = threadIdx.x;
    int wg = blockIdx.x;
    if (t < 64) {
        int m = wg * 64 + t;
        int bb = m & 3, ss = m >> 2;
        xi[t] = x[bb * S_LEN + ss];
    }
    __syncthreads();

    int wv = t >> 6, l = t & 63, lr = l & 15, lg = l >> 4;

    f32x4v acc[32];
#pragma unroll
    for (int i = 0; i < 32; i++) acc[i] = (f32x4v){0.f, 0.f, 0.f, 0.f};

    for (int kc = 0; kc < 512; kc += 32) {
        __syncthreads();
        {
            int tk = t >> 2, c0 = (t & 3) * 8;
            const float* src = emb + (size_t)xi[tk] * NS + kc + c0;
            float4 v0 = *(const float4*)src;
            float4 v1 = *(const float4*)(src + 4);
            f16x8 h;
            h[0] = (f16)v0.x; h[1] = (f16)v0.y; h[2] = (f16)v0.z; h[3] = (f16)v0.w;
            h[4] = (f16)v1.x; h[5] = (f16)v1.y; h[6] = (f16)v1.z; h[7] = (f16)v1.w;
            *(f16x8*)&embA[tk * 40 + c0] = h;
        }
        {
            int c0 = (t & 3) * 8;
            int n0 = t >> 2;
#pragma unroll
            for (int rr = 0; rr < 8; rr++) {
                int n = rr * 64 + n0;
                f16x8 v = *(const f16x8*)&bT[n * 512 + kc + c0];
                *(f16x8*)&Bt[n * 40 + c0] = v;
            }
        }
        __syncthreads();

        f16x8 af = *(const f16x8*)&embA[(wv * 16 + lr) * 40 + 8 * lg];
#pragma unroll
        for (int vt = 0; vt < 32; vt++) {
            f16x8 bf = *(const f16x8*)&Bt[(vt * 16 + lr) * 40 + 8 * lg];
            acc[vt] = MFMA16(af, bf, acc[vt]);
        }
    }

    int m0 = wg * 64 + wv * 16 + 4 * lg;
    int ss = m0 >> 2;
#pragma unroll
    for (int vt = 0; vt < 32; vt++) {
        int n = vt * 16 + lr;
        f16x4 h;
#pragma unroll
        for (int i = 0; i < 4; i++) h[i] = (f16)acc[vt][i];
        *(f16x4*)&u16[((size_t)ss * NS + n) * 4] = h;
    }
}

// ---------------------------------------------------------------------------
// scan on 4 CUs (blocks 0..3). Each CU owns 128 n-columns; A-slice fully in
// registers (64 VGPR/lane). Cross-CU exchange: write-once X[s][col] with
// sentinel pre-fill; consumers DATA-POLL (single LLC round trip, no flags,
// no store-ack gate). One barrier per step (double-buffered LDS state).
// ---------------------------------------------------------------------------
__global__ __launch_bounds__(512) void scan_kernel(
        const float* __restrict__ a, const f16* __restrict__ u16,
        f16* __restrict__ st16, unsigned long long* __restrict__ X) {
    __shared__ f16 Sb[2][4][544];   // [buf][batch][col(+pad)] full 512-state

    int t = threadIdx.x;
    int r = blockIdx.x;                 // worker rank 0..3
    int w = t >> 6, l = t & 63, lr = l & 15, lg = l >> 4;
    int col = r * 128 + w * 16 + lr;    // this lane's output column

    // gather assignment: waves 0..5 each own one remote 64-col chunk
    int gcol = -1;
    if (w < 6) {
        int cw = w + (w >= 2 * r ? 2 : 0);   // skip own chunks {2r, 2r+1}
        gcol = cw * 64 + l;
    }

    // zero both state buffers
    for (int i = t; i < 2 * 4 * 544; i += 512) ((f16*)Sb)[i] = (f16)0.f;

    // stationary A fragments: afr[ks][j] = a[ks*32 + 8*lg + j][col]  (64 VGPR)
    f16x8 afr[16];
#pragma unroll
    for (int ks = 0; ks < 16; ks++) {
        f16x8 h;
#pragma unroll
        for (int j = 0; j < 8; j++)
            h[j] = (f16)a[(size_t)(ks * 32 + 8 * lg + j) * NS + col];
        afr[ks] = h;
    }

    // u prefetch for step 0 (batch-packed u64 per column)
    f16x4 upf = *(const f16x4*)&u16[(size_t)col * 4];

    __syncthreads();

#pragma unroll 1
    for (int s = 0; s < S_LEN; s++) {
        int cur = s & 1, nxt = cur ^ 1;

        f32x4v acca, accb;
        acca[0] = (float)upf[0]; acca[1] = (float)upf[1];
        acca[2] = (float)upf[2]; acca[3] = (float)upf[3];
        accb = (f32x4v){0.f, 0.f, 0.f, 0.f};

        // prefetch next step's u (hidden under MFMAs)
        {
            int sn = (s + 1 < S_LEN) ? s + 1 : S_LEN - 1;
            upf = *(const f16x4*)&u16[((size_t)sn * NS + col) * 4];
        }

        // Y = S @ A : 16 k-slices, state from LDS (4-row broadcast), A in regs
        const char* sb = (const char*)Sb + cur * 4352 + (lr & 3) * 1088 + lg * 16;
#pragma unroll
        for (int ks = 0; ks < 16; ks += 2) {
            f16x8 s0 = *(const f16x8*)(sb + ks * 64);
            f16x8 s1 = *(const f16x8*)(sb + ks * 64 + 64);
            acca = MFMA16(s0, afr[ks], acca);
            accb = MFMA16(s1, afr[ks + 1], accb);
        }

        // tanh + publish own 16-col tile: X store FIRST (fire-and-forget)
        if (lg == 0) {
            union { unsigned long long u; f16 h[4]; } pk;
#pragma unroll
            for (int i = 0; i < 4; i++) {
                float y = acca[i] + accb[i];
                float e = __expf(2.0f * y);
                float rc = __builtin_amdgcn_rcpf(e + 1.0f);
                y = __builtin_fmaf(-2.0f, rc, 1.0f);   // tanh
                pk.h[i] = (f16)y;
            }
            __hip_atomic_store(&X[(size_t)s * NS + col], pk.u,
                               __ATOMIC_RELAXED, __HIP_MEMORY_SCOPE_AGENT);
#pragma unroll
            for (int i = 0; i < 4; i++) {
                Sb[nxt][i][col] = pk.h[i];
                st16[((size_t)s * 4 + i) * NS + col] = pk.h[i];
            }
        }

        if (s == S_LEN - 1) break;

        // data-poll gather: one u64 per lane, waves 0..5 (384 remote cols)
        if (w < 6) {
            unsigned long long v;
            do {
                v = __hip_atomic_load(&X[(size_t)s * NS + gcol],
                                      __ATOMIC_RELAXED,
                                      __HIP_MEMORY_SCOPE_AGENT);
            } while (v == SENT);
            union { unsigned long long u; f16 h[4]; } pk;
            pk.u = v;
#pragma unroll
            for (int i = 0; i < 4; i++) Sb[nxt][i][gcol] = pk.h[i];
        }

        // single barrier per step: all LDS reads+writes of step s complete
        asm volatile("s_waitcnt lgkmcnt(0)" ::: "memory");
        __builtin_amdgcn_s_barrier();
        __builtin_amdgcn_sched_barrier(0);
    }
}

// ---------------------------------------------------------------------------
// readout: out[b][s][v] = states[s*4+b] . c_w[v] + c_b[v]
// ---------------------------------------------------------------------------
__global__ __launch_bounds__(512) void readout_kernel(
        const f16* __restrict__ st16, const float* __restrict__ cw,
        const float* __restrict__ cb, float* __restrict__ out) {
    __shared__ f16 Ast[256 * 72];
    __shared__ f16 Bw[128 * 72];

    int t = threadIdx.x;
    int bidx = blockIdx.x;
    int bn = bidx % 250;
    int bm = bidx / 250;
    int w = t >> 6, l = t & 63, lr = l & 15, lg = l >> 4;
    int wr = w >> 1, wc = w & 1;

    f32x4v acc[4][4];
#pragma unroll
    for (int i = 0; i < 4; i++)
#pragma unroll
        for (int j = 0; j < 4; j++) acc[i][j] = (f32x4v){0.f, 0.f, 0.f, 0.f};

    for (int kc = 0; kc < 512; kc += 64) {
        __syncthreads();
#pragma unroll
        for (int q = 0; q < 4; q++) {
            int idx = q * 512 + t;
            int row = idx >> 3;
            int c0 = (idx & 7) * 8;
            f16x8 v = *(const f16x8*)&st16[(size_t)(bm * 256 + row) * NS + kc + c0];
            *(f16x8*)&Ast[row * 72 + c0] = v;
        }
#pragma unroll
        for (int q = 0; q < 4; q++) {
            int idx = q * 512 + t;
            int row = idx >> 4;
            int c0 = (idx & 15) * 4;
            float4 v = *(const float4*)&cw[(size_t)(bn * 128 + row) * NS + kc + c0];
            f16x4 h;
            h[0] = (f16)v.x; h[1] = (f16)v.y; h[2] = (f16)v.z; h[3] = (f16)v.w;
            *(f16x4*)&Bw[row * 72 + c0] = h;
        }
        __syncthreads();

#pragma unroll
        for (int ks = 0; ks < 2; ks++) {
            f16x8 af[4], bf[4];
#pragma unroll
            for (int mt = 0; mt < 4; mt++)
                af[mt] = *(const f16x8*)&Ast[(wr * 64 + mt * 16 + lr) * 72 +
                                             ks * 32 + 8 * lg];
#pragma unroll
            for (int vt = 0; vt < 4; vt++)
                bf[vt] = *(const f16x8*)&Bw[(wc * 64 + vt * 16 + lr) * 72 +
                                            ks * 32 + 8 * lg];
#pragma unroll
            for (int mt = 0; mt < 4; mt++)
#pragma unroll
                for (int vt = 0; vt < 4; vt++)
                    acc[mt][vt] = MFMA16(af[mt], bf[vt], acc[mt][vt]);
        }
    }

    float bias[4];
#pragma unroll
    for (int vt = 0; vt < 4; vt++)
        bias[vt] = cb[bn * 128 + wc * 64 + vt * 16 + lr];

#pragma unroll
    for (int mt = 0; mt < 4; mt++) {
#pragma unroll
        for (int i = 0; i < 4; i++) {
            int m = bm * 256 + wr * 64 + mt * 16 + 4 * lg + i;
            int bb = m & 3, ss = m >> 2;
            float* orow = out + (size_t)(bb * S_LEN + ss) * NV + bn * 128 + wc * 64;
#pragma unroll
            for (int vt = 0; vt < 4; vt++)
                orow[vt * 16 + lr] = acc[mt][vt][i] + bias[vt];
        }
    }
}

// ---------------------------------------------------------------------------
extern "C" void kernel_launch(void* const* d_in, const int* in_sizes, int n_in,
                              void* d_out, int out_size, void* d_ws, size_t ws_size,
                              hipStream_t stream) {
    (void)in_sizes; (void)n_in; (void)out_size; (void)ws_size;

    const int*   x   = (const int*)d_in[0];
    const float* emb = (const float*)d_in[1];
    const float* a   = (const float*)d_in[2];
    const float* bm  = (const float*)d_in[3];
    const float* cw  = (const float*)d_in[4];
    const float* cb  = (const float*)d_in[5];
    float* out = (float*)d_out;

    char* ws = (char*)d_ws;
    f16* u16  = (f16*)(ws);
    f16* st16 = (f16*)(ws + (4u << 20));
    unsigned long long* X = (unsigned long long*)(ws + (8u << 20));
    f16* bT16 = (f16*)(ws + (12u << 20));

    transpose512_f16_kernel<<<1024, 256, 0, stream>>>(bm, bT16, X);
    embu_kernel<<<64, 256, 0, stream>>>(x, emb, bT16, u16);
    scan_kernel<<<NW, 512, 0, stream>>>(a, u16, st16, X);
    readout_kernel<<<16 * 250, 512, 0, stream>>>(st16, cw, cb, out);
}

// Round 7
// 1351.310 us; speedup vs baseline: 6.8942x; 1.1088x over previous
//
#include <hip/hip_runtime.h>
#include <hip/hip_fp16.h>

typedef _Float16 f16;
typedef _Float16 f16x8 __attribute__((ext_vector_type(8)));
typedef _Float16 f16x4 __attribute__((ext_vector_type(4)));
typedef float f32x4v __attribute__((ext_vector_type(4)));
typedef unsigned long long u64;

#define S_LEN 1024
#define NS 512
#define NV 32000
#define NW 4          // scan workers (CUs)
#define SENT 0x7C007C007C007C00ULL   // 4x f16 +inf: unreachable for tanh output
#define FUSED_LDS 98304              // >80KB -> exactly 1 block/CU

#define MFMA16(a, b, c) __builtin_amdgcn_mfma_f32_16x16x32_f16((a), (b), (c), 0, 0, 0)

// ---------------------------------------------------------------------------
// ws layout:
//   u16   : [1024][512][4] f16  at 0      (4 MB)   u[s][n][b]  (batch-packed)
//   X     : u64[1024][512]      at 4 MB   (4 MB)   state record + exchange
//   bT16  : [512][512]     f16  at 8 MB   (512 KB)
// ---------------------------------------------------------------------------

// transpose b -> f16, and refill X with sentinel (every launch; graph-safe)
__global__ __launch_bounds__(256) void transpose512_f16_kernel(
        const float* __restrict__ src, f16* __restrict__ dstT,
        u64* __restrict__ X) {
    int idx = blockIdx.x * 256 + threadIdx.x;   // 0..262143
    X[idx] = SENT;
    X[idx + 262144] = SENT;
    int r = idx >> 9;
    int c = idx & 511;
    dstT[c * 512 + r] = (f16)src[idx];
}

// ---------------------------------------------------------------------------
// embed + input projection: u[m][n] = sum_e emb[x[m]][e] * b[e][n], m = s*4+b
// ---------------------------------------------------------------------------
__global__ __launch_bounds__(256) void embu_kernel(
        const int* __restrict__ x, const float* __restrict__ emb,
        const f16* __restrict__ bT, f16* __restrict__ u16) {
    __shared__ f16 embA[64 * 40];
    __shared__ f16 Bt[512 * 40];
    __shared__ int xi[64];

    int t = threadIdx.x;
    int wg = blockIdx.x;
    if (t < 64) {
        int m = wg * 64 + t;
        int bb = m & 3, ss = m >> 2;
        xi[t] = x[bb * S_LEN + ss];
    }
    __syncthreads();

    int wv = t >> 6, l = t & 63, lr = l & 15, lg = l >> 4;

    f32x4v acc[32];
#pragma unroll
    for (int i = 0; i < 32; i++) acc[i] = (f32x4v){0.f, 0.f, 0.f, 0.f};

    for (int kc = 0; kc < 512; kc += 32) {
        __syncthreads();
        {
            int tk = t >> 2, c0 = (t & 3) * 8;
            const float* src = emb + (size_t)xi[tk] * NS + kc + c0;
            float4 v0 = *(const float4*)src;
            float4 v1 = *(const float4*)(src + 4);
            f16x8 h;
            h[0] = (f16)v0.x; h[1] = (f16)v0.y; h[2] = (f16)v0.z; h[3] = (f16)v0.w;
            h[4] = (f16)v1.x; h[5] = (f16)v1.y; h[6] = (f16)v1.z; h[7] = (f16)v1.w;
            *(f16x8*)&embA[tk * 40 + c0] = h;
        }
        {
            int c0 = (t & 3) * 8;
            int n0 = t >> 2;
#pragma unroll
            for (int rr = 0; rr < 8; rr++) {
                int n = rr * 64 + n0;
                f16x8 v = *(const f16x8*)&bT[n * 512 + kc + c0];
                *(f16x8*)&Bt[n * 40 + c0] = v;
            }
        }
        __syncthreads();

        f16x8 af = *(const f16x8*)&embA[(wv * 16 + lr) * 40 + 8 * lg];
#pragma unroll
        for (int vt = 0; vt < 32; vt++) {
            f16x8 bf = *(const f16x8*)&Bt[(vt * 16 + lr) * 40 + 8 * lg];
            acc[vt] = MFMA16(af, bf, acc[vt]);
        }
    }

    int m0 = wg * 64 + wv * 16 + 4 * lg;
    int ss = m0 >> 2;
#pragma unroll
    for (int vt = 0; vt < 32; vt++) {
        int n = vt * 16 + lr;
        f16x4 h;
#pragma unroll
        for (int i = 0; i < 4; i++) h[i] = (f16)acc[vt][i];
        *(f16x4*)&u16[((size_t)ss * NS + n) * 4] = h;
    }
}

// ---------------------------------------------------------------------------
// FUSED scan + readout.
//   blocks 0..3      : scan (4 CUs, col-partitioned, data-poll exchange via X)
//   blocks 4..4003   : readout tiles, bm-major; gate on canary, stage A from X
// 96 KB dynamic LDS -> 1 block/CU, so readout never shares a CU with scan.
// ---------------------------------------------------------------------------
__global__ __launch_bounds__(512) void fused_kernel(
        const float* __restrict__ a, const f16* __restrict__ u16,
        const float* __restrict__ cw, const float* __restrict__ cb,
        u64* __restrict__ X, float* __restrict__ out) {
    extern __shared__ char smem[];
    int t = threadIdx.x;
    int bid = blockIdx.x;
    int w = t >> 6, l = t & 63, lr = l & 15, lg = l >> 4;

    if (bid < NW) {
        // ================= scan =================
        f16* Sb = (f16*)smem;               // [2][4][544] f16
        int r = bid;
        int col = r * 128 + w * 16 + lr;

        int gcol = -1;
        if (w < 6) {
            int cwk = w + (w >= 2 * r ? 2 : 0);   // skip own chunks {2r,2r+1}
            gcol = cwk * 64 + l;
        }

        for (int i = t; i < 2 * 4 * 544; i += 512) Sb[i] = (f16)0.f;

        // stationary A fragments (64 VGPR/lane)
        f16x8 afr[16];
#pragma unroll
        for (int ks = 0; ks < 16; ks++) {
            f16x8 h;
#pragma unroll
            for (int j = 0; j < 8; j++)
                h[j] = (f16)a[(size_t)(ks * 32 + 8 * lg + j) * NS + col];
            afr[ks] = h;
        }

        f16x4 upf = *(const f16x4*)&u16[(size_t)col * 4];

        __syncthreads();

#pragma unroll 1
        for (int s = 0; s < S_LEN; s++) {
            int cur = s & 1, nxt = cur ^ 1;

            f32x4v acca, accb;
            acca[0] = (float)upf[0]; acca[1] = (float)upf[1];
            acca[2] = (float)upf[2]; acca[3] = (float)upf[3];
            accb = (f32x4v){0.f, 0.f, 0.f, 0.f};

            {
                int sn = (s + 1 < S_LEN) ? s + 1 : S_LEN - 1;
                upf = *(const f16x4*)&u16[((size_t)sn * NS + col) * 4];
            }

            const char* sb = (const char*)Sb + cur * 4352 +
                             (lr & 3) * 1088 + lg * 16;
#pragma unroll
            for (int ks = 0; ks < 16; ks += 2) {
                f16x8 s0 = *(const f16x8*)(sb + ks * 64);
                f16x8 s1 = *(const f16x8*)(sb + ks * 64 + 64);
                acca = MFMA16(s0, afr[ks], acca);
                accb = MFMA16(s1, afr[ks + 1], accb);
            }

            // tanh + publish: X store first (fire-and-forget), then LDS
            if (lg == 0) {
                union { u64 u; f16 h[4]; } pk;
#pragma unroll
                for (int i = 0; i < 4; i++) {
                    float y = acca[i] + accb[i];
                    float e = __expf(2.0f * y);
                    float rc = __builtin_amdgcn_rcpf(e + 1.0f);
                    y = __builtin_fmaf(-2.0f, rc, 1.0f);   // tanh
                    pk.h[i] = (f16)y;
                }
                __hip_atomic_store(&X[(size_t)s * NS + col], pk.u,
                                   __ATOMIC_RELAXED, __HIP_MEMORY_SCOPE_AGENT);
#pragma unroll
                for (int i = 0; i < 4; i++)
                    Sb[nxt * 2176 + i * 544 + col] = pk.h[i];
            }

            if (s == S_LEN - 1) break;

            // data-poll gather: waves 0..5, one remote u64 per lane
            if (w < 6) {
                u64 v;
                do {
                    v = __hip_atomic_load(&X[(size_t)s * NS + gcol],
                                          __ATOMIC_RELAXED,
                                          __HIP_MEMORY_SCOPE_AGENT);
                } while (v == SENT);
                union { u64 u; f16 h[4]; } pk;
                pk.u = v;
#pragma unroll
                for (int i = 0; i < 4; i++)
                    Sb[nxt * 2176 + i * 544 + gcol] = pk.h[i];
            }

            asm volatile("s_waitcnt lgkmcnt(0)" ::: "memory");
            __builtin_amdgcn_s_barrier();
            __builtin_amdgcn_sched_barrier(0);
        }
        return;
    }

    // ================= readout =================
    f16* Ast = (f16*)smem;                 // [256][72]
    f16* Bw = (f16*)(smem + 256 * 72 * 2); // [128][72]

    int idx = bid - NW;
    int bm = idx / 250;      // bm-major: early blocks handle early s
    int bn = idx % 250;
    int s0 = bm * 64;

    // canary gate: scan past our s-range (per-element polls below are the
    // airtight correctness check; this just avoids a poll storm)
    if (t == 0) {
        int sc = (bm == 15) ? (S_LEN - 1) : (s0 + 64);
        while (__hip_atomic_load(&X[(size_t)sc * NS], __ATOMIC_RELAXED,
                                 __HIP_MEMORY_SCOPE_AGENT) == SENT)
            __builtin_amdgcn_s_sleep(16);
    }
    __syncthreads();

    int wr = w >> 1, wc = w & 1;

    f32x4v acc[4][4];
#pragma unroll
    for (int i = 0; i < 4; i++)
#pragma unroll
        for (int j = 0; j < 4; j++) acc[i][j] = (f32x4v){0.f, 0.f, 0.f, 0.f};

    for (int kc = 0; kc < 512; kc += 64) {
        __syncthreads();
        // stage A from X: 64 s x 64 cols of u64; per-element sentinel poll
        {
            int srel = t >> 3;
            int ck = (t & 7) * 8;
            const u64* xs = &X[(size_t)(s0 + srel) * NS + kc + ck];
            u64 v[8];
#pragma unroll
            for (int j = 0; j < 8; j++)
                v[j] = __hip_atomic_load(&xs[j], __ATOMIC_RELAXED,
                                         __HIP_MEMORY_SCOPE_AGENT);
#pragma unroll
            for (int j = 0; j < 8; j++)
                while (v[j] == SENT)
                    v[j] = __hip_atomic_load(&xs[j], __ATOMIC_RELAXED,
                                             __HIP_MEMORY_SCOPE_AGENT);
#pragma unroll
            for (int j = 0; j < 8; j++) {
                union { u64 u; f16 h[4]; } pk;
                pk.u = v[j];
#pragma unroll
                for (int b = 0; b < 4; b++)
                    Ast[(srel * 4 + b) * 72 + ck + j] = pk.h[b];
            }
        }
        // stage B: c_w fp32 -> f16
#pragma unroll
        for (int q = 0; q < 4; q++) {
            int i2 = q * 512 + t;
            int row = i2 >> 4;
            int c0 = (i2 & 15) * 4;
            float4 v = *(const float4*)&cw[(size_t)(bn * 128 + row) * NS + kc + c0];
            f16x4 h;
            h[0] = (f16)v.x; h[1] = (f16)v.y; h[2] = (f16)v.z; h[3] = (f16)v.w;
            *(f16x4*)&Bw[row * 72 + c0] = h;
        }
        __syncthreads();

#pragma unroll
        for (int ks = 0; ks < 2; ks++) {
            f16x8 af[4], bf[4];
#pragma unroll
            for (int mt = 0; mt < 4; mt++)
                af[mt] = *(const f16x8*)&Ast[(wr * 64 + mt * 16 + lr) * 72 +
                                             ks * 32 + 8 * lg];
#pragma unroll
            for (int vt = 0; vt < 4; vt++)
                bf[vt] = *(const f16x8*)&Bw[(wc * 64 + vt * 16 + lr) * 72 +
                                            ks * 32 + 8 * lg];
#pragma unroll
            for (int mt = 0; mt < 4; mt++)
#pragma unroll
                for (int vt = 0; vt < 4; vt++)
                    acc[mt][vt] = MFMA16(af[mt], bf[vt], acc[mt][vt]);
        }
    }

    float bias[4];
#pragma unroll
    for (int vt = 0; vt < 4; vt++)
        bias[vt] = cb[bn * 128 + wc * 64 + vt * 16 + lr];

#pragma unroll
    for (int mt = 0; mt < 4; mt++) {
#pragma unroll
        for (int i = 0; i < 4; i++) {
            int m = bm * 256 + wr * 64 + mt * 16 + 4 * lg + i;
            int bb = m & 3, ss = m >> 2;
            float* orow = out + (size_t)(bb * S_LEN + ss) * NV + bn * 128 + wc * 64;
#pragma unroll
            for (int vt = 0; vt < 4; vt++)
                orow[vt * 16 + lr] = acc[mt][vt][i] + bias[vt];
        }
    }
}

// ---------------------------------------------------------------------------
extern "C" void kernel_launch(void* const* d_in, const int* in_sizes, int n_in,
                              void* d_out, int out_size, void* d_ws, size_t ws_size,
                              hipStream_t stream) {
    (void)in_sizes; (void)n_in; (void)out_size; (void)ws_size;

    const int*   x   = (const int*)d_in[0];
    const float* emb = (const float*)d_in[1];
    const float* a   = (const float*)d_in[2];
    const float* bm  = (const float*)d_in[3];
    const float* cw  = (const float*)d_in[4];
    const float* cb  = (const float*)d_in[5];
    float* out = (float*)d_out;

    char* ws = (char*)d_ws;
    f16* u16 = (f16*)(ws);
    u64* X   = (u64*)(ws + (4u << 20));
    f16* bT16 = (f16*)(ws + (8u << 20));

    hipFuncSetAttribute(reinterpret_cast<const void*>(fused_kernel),
                        hipFuncAttributeMaxDynamicSharedMemorySize,
                        FUSED_LDS);

    transpose512_f16_kernel<<<1024, 256, 0, stream>>>(bm, bT16, X);
    embu_kernel<<<64, 256, 0, stream>>>(x, emb, bT16, u16);
    fused_kernel<<<NW + 16 * 250, 512, FUSED_LDS, stream>>>(
        a, u16, cw, cb, X, out);
}